// Round 3
// baseline (603.619 us; speedup 1.0000x reference)
//
#include <hip/hip_runtime.h>
#include <cmath>

// ---------------------------------------------------------------------------
// Problem constants: B=16, N=196, D=512, M=20, H=8, hd=64, k=51
//   tokens = 3136, 3D = 1536
// ---------------------------------------------------------------------------

// Generic small GEMM, fp32 storage, fp32 FMA with fp64 chunk accumulation.
// C[i,j] = sum_k A[i,k] * B'[k,j]  (+bias[j]) (+res[i*ldc+j])
//   bTrans=1: B is [N][K] row-major (we dot rows)      -> B'[k,j] = B[j*ldb+k]
//   bTrans=0: B is [K][N] row-major                    -> B'[k,j] = B[k*ldb+j]
// Batched via blockIdx.z: off = (z/zInner)*Outer + (z%zInner)*Inner per operand.
__global__ __launch_bounds__(256) void gemm_kernel(
    const float* __restrict__ A, const float* __restrict__ B,
    float* __restrict__ C, const float* __restrict__ bias,
    const float* __restrict__ res,
    int M, int N, int K, int lda, int ldb, int ldc,
    int zInner, long long aOuter, long long aInner,
    long long bOuter, long long bInner,
    long long cOuter, long long cInner, int bTrans)
{
  int z = blockIdx.z;
  int zo = z / zInner, zi = z % zInner;
  A += zo * aOuter + zi * aInner;
  B += zo * bOuter + zi * bInner;
  C += zo * cOuter + zi * cInner;

  __shared__ __align__(16) float As[16][68];
  __shared__ __align__(16) float Bs[16][68];

  int tid = threadIdx.x;
  int tx = tid & 15, ty = tid >> 4;
  int i0 = blockIdx.x * 64, j0 = blockIdx.y * 64;

  double acc[4][4];
#pragma unroll
  for (int i = 0; i < 4; i++)
#pragma unroll
    for (int j = 0; j < 4; j++) acc[i][j] = 0.0;

  for (int k0 = 0; k0 < K; k0 += 16) {
    // stage A tile [64 rows][16 k] -> As[k][row]
#pragma unroll
    for (int rr = 0; rr < 4; rr++) {
      int r = ty + 16 * rr;
      int gi = i0 + r, gk = k0 + tx;
      As[tx][r] = (gi < M && gk < K) ? A[(size_t)gi * lda + gk] : 0.0f;
    }
    if (bTrans) {
#pragma unroll
      for (int rr = 0; rr < 4; rr++) {
        int r = ty + 16 * rr;
        int gj = j0 + r, gk = k0 + tx;
        Bs[tx][r] = (gj < N && gk < K) ? B[(size_t)gj * ldb + gk] : 0.0f;
      }
    } else {
      int j = tid & 63, c0 = (tid >> 6) * 4;
#pragma unroll
      for (int cc = 0; cc < 4; cc++) {
        int c = c0 + cc;
        int gk = k0 + c, gj = j0 + j;
        Bs[c][j] = (gk < K && gj < N) ? B[(size_t)gk * ldb + gj] : 0.0f;
      }
    }
    __syncthreads();

    float cf[4][4];
#pragma unroll
    for (int i = 0; i < 4; i++)
#pragma unroll
      for (int j = 0; j < 4; j++) cf[i][j] = 0.0f;
#pragma unroll
    for (int kk = 0; kk < 16; kk++) {
      float4 a4 = *(const float4*)&As[kk][ty * 4];
      float4 b4 = *(const float4*)&Bs[kk][tx * 4];
      float av[4] = {a4.x, a4.y, a4.z, a4.w};
      float bv[4] = {b4.x, b4.y, b4.z, b4.w};
#pragma unroll
      for (int i = 0; i < 4; i++)
#pragma unroll
        for (int j = 0; j < 4; j++) cf[i][j] = fmaf(av[i], bv[j], cf[i][j]);
    }
#pragma unroll
    for (int i = 0; i < 4; i++)
#pragma unroll
      for (int j = 0; j < 4; j++) acc[i][j] += (double)cf[i][j];
    __syncthreads();
  }

#pragma unroll
  for (int i = 0; i < 4; i++) {
    int gi = i0 + ty * 4 + i;
    if (gi >= M) continue;
    int gj0 = j0 + tx * 4;
    if (gj0 >= N) continue;  // all our N are multiples of 4
    float ov[4];
#pragma unroll
    for (int j = 0; j < 4; j++) {
      double v = acc[i][j];
      if (bias) v += (double)bias[gj0 + j];
      if (res)  v += (double)res[(size_t)gi * ldc + gj0 + j];
      ov[j] = (float)v;
    }
    float4 o; o.x = ov[0]; o.y = ov[1]; o.z = ov[2]; o.w = ov[3];
    *(float4*)&C[(size_t)gi * ldc + gj0] = o;
  }
}

// In-place row softmax of scaled scores: rows of length 196, scale 1/sqrt(64).
// One wave per row, 4 rows per block. fp64 internal.
__global__ __launch_bounds__(256) void softmax_kernel(float* __restrict__ S)
{
  int row = blockIdx.x * 4 + (threadIdx.x >> 6);
  int lane = threadIdx.x & 63;
  float* sr = S + (size_t)row * 196;
  double v[4];
#pragma unroll
  for (int t = 0; t < 4; t++) {
    int j = lane + 64 * t;
    v[t] = (j < 196) ? (double)sr[j] * 0.125 : -1e300;
  }
  double mx = fmax(fmax(v[0], v[1]), fmax(v[2], v[3]));
#pragma unroll
  for (int off = 1; off < 64; off <<= 1) mx = fmax(mx, __shfl_xor(mx, off));
  double e[4]; double s = 0.0;
#pragma unroll
  for (int t = 0; t < 4; t++) {
    int j = lane + 64 * t;
    e[t] = (j < 196) ? exp(v[t] - mx) : 0.0;
    s += e[t];
  }
#pragma unroll
  for (int off = 1; off < 64; off <<= 1) s += __shfl_xor(s, off);
  double inv = 1.0 / s;
#pragma unroll
  for (int t = 0; t < 4; t++) {
    int j = lane + 64 * t;
    if (j < 196) sr[j] = (float)(e[t] * inv);
  }
}

// In-place LayerNorm (ddof=0, eps=1e-5) + exact GELU over rows of 512.
__global__ __launch_bounds__(256) void lngelu_kernel(float* __restrict__ H,
    const float* __restrict__ g, const float* __restrict__ bb)
{
  int row = blockIdx.x;
  float* hr = H + (size_t)row * 512;
  int tid = threadIdx.x, lane = tid & 63, wv = tid >> 6;
  __shared__ double red[8];
  double x0 = (double)hr[tid], x1 = (double)hr[tid + 256];
  double s = x0 + x1;
#pragma unroll
  for (int off = 1; off < 64; off <<= 1) s += __shfl_xor(s, off);
  if (lane == 0) red[wv] = s;
  __syncthreads();
  double mu = (red[0] + red[1] + red[2] + red[3]) * (1.0 / 512.0);
  double d0 = x0 - mu, d1 = x1 - mu;
  double q = d0 * d0 + d1 * d1;
#pragma unroll
  for (int off = 1; off < 64; off <<= 1) q += __shfl_xor(q, off);
  if (lane == 0) red[4 + wv] = q;
  __syncthreads();
  double var = (red[4] + red[5] + red[6] + red[7]) * (1.0 / 512.0);
  double inv = 1.0 / sqrt(var + 1e-5);
  double y0 = d0 * inv * (double)g[tid]       + (double)bb[tid];
  double y1 = d1 * inv * (double)g[tid + 256] + (double)bb[tid + 256];
  const double ISQRT2 = 0.70710678118654752440;
  double z0 = 0.5 * y0 * (1.0 + erf(y0 * ISQRT2));
  double z1 = 0.5 * y1 * (1.0 + erf(y1 * ISQRT2));
  hr[tid] = (float)z0;
  hr[tid + 256] = (float)z1;
}

// Qp[token,m] = h[token,:] . w2[m,:] + b2[m] ; fp64 accumulate. 62720 outputs.
__global__ __launch_bounds__(256) void w2_kernel(const float* __restrict__ H,
    const float* __restrict__ W2, const float* __restrict__ B2,
    float* __restrict__ Qp)
{
  int gidx = blockIdx.x * 256 + threadIdx.x;  // grid 245*256 == 62720 exactly
  int token = gidx / 20, m = gidx % 20;
  const float* hr = H + (size_t)token * 512;
  const float* wr = W2 + (size_t)m * 512;
  double acc = 0.0;
  for (int k = 0; k < 512; k += 4) {
    float4 hv = *(const float4*)&hr[k];
    float4 wv = *(const float4*)&wr[k];
    acc += (double)hv.x * wv.x + (double)hv.y * wv.y +
           (double)hv.z * wv.z + (double)hv.w * wv.w;
  }
  Qp[gidx] = (float)(acc + (double)B2[m]);
}

// Final: per (b,n,m) abs-top-51 over D of A = (F*T)*Qp, 0/1 mask, L2-normalize,
// write out[b,n,d,m]. Selection key = exact double product |F*T| (bit-exact vs
// a float64 reference), tie-break by lower d via ballot ranks.
__global__ __launch_bounds__(256) void topk_kernel(
    const float* __restrict__ F, const float* __restrict__ T,
    const float* __restrict__ Qp, float* __restrict__ out)
{
  const int KSEL = 51;
  int bn = blockIdx.x;
  int tid = threadIdx.x, lane = tid & 63, wv = tid >> 6;
  __shared__ float tile[512 * 21];  // [d][m], padded row stride 21
  const float* Frow = F + (size_t)bn * 512;
  double f[8];
#pragma unroll
  for (int s = 0; s < 8; s++) f[s] = (double)Frow[lane + 64 * s];

  for (int m = wv; m < 20; m += 4) {
    double qp = (double)Qp[(size_t)bn * 20 + m];
    const float* Trow = T + (size_t)m * 512;
    double a[8];
    unsigned long long u[8];
#pragma unroll
    for (int s = 0; s < 8; s++) {
      double p = f[s] * (double)Trow[lane + 64 * s];  // exact in fp64
      a[s] = p * qp;
      u[s] = ((unsigned long long)__double_as_longlong(p)) & 0x7fffffffffffffffULL;
    }
    // binary search smallest threshold with count(u >= thr) >= 51
    unsigned long long lo = 0ULL, hi = 0x7ff0000000000000ULL;
    while (hi - lo > 1ULL) {
      unsigned long long mid = lo + ((hi - lo) >> 1);
      int c = 0;
#pragma unroll
      for (int s = 0; s < 8; s++) c += (u[s] >= mid) ? 1 : 0;
#pragma unroll
      for (int off = 1; off < 64; off <<= 1) c += __shfl_xor(c, off);
      if (c >= KSEL) { lo = mid; if (c == KSEL) break; }
      else hi = mid;
    }
    unsigned long long thr = lo;
    int cg = 0;
#pragma unroll
    for (int s = 0; s < 8; s++) cg += (u[s] > thr) ? 1 : 0;
#pragma unroll
    for (int off = 1; off < 64; off <<= 1) cg += __shfl_xor(cg, off);
    int need_eq = KSEL - cg;  // how many ==thr to take, in increasing d order
    unsigned long long lmask = (1ULL << lane) - 1ULL;
    bool sel[8];
    int base = 0;
#pragma unroll
    for (int s = 0; s < 8; s++) {   // d = lane + 64*s: (s,lane) lexicographic == d order
      bool iseq = (u[s] == thr);
      unsigned long long bal = __ballot((int)iseq);
      int rk = base + __popcll(bal & lmask);
      sel[s] = (u[s] > thr) || (iseq && rk < need_eq);
      base += __popcll(bal);
    }
    double ss = 0.0;
#pragma unroll
    for (int s = 0; s < 8; s++) if (sel[s]) ss += a[s] * a[s];
#pragma unroll
    for (int off = 1; off < 64; off <<= 1) ss += __shfl_xor(ss, off);
    double inv = 1.0 / fmax(sqrt(ss), 1e-6);
#pragma unroll
    for (int s = 0; s < 8; s++)
      tile[(lane + 64 * s) * 21 + m] = sel[s] ? (float)(a[s] * inv) : 0.0f;
  }
  __syncthreads();

  // coalesced writeout: [512][20] contiguous per (b,n)
  float* orow = out + (size_t)bn * 10240;
#pragma unroll
  for (int it = 0; it < 10; it++) {
    int i = it * 256 + tid;  // float4 index, 2560 total
    int j = i * 4;
    float4 o;
    o.x = tile[((j + 0) / 20) * 21 + (j + 0) % 20];
    o.y = tile[((j + 1) / 20) * 21 + (j + 1) % 20];
    o.z = tile[((j + 2) / 20) * 21 + (j + 2) % 20];
    o.w = tile[((j + 3) / 20) * 21 + (j + 3) % 20];
    *(float4*)&orow[j] = o;
  }
}

extern "C" void kernel_launch(void* const* d_in, const int* in_sizes, int n_in,
                              void* d_out, int out_size, void* d_ws, size_t ws_size,
                              hipStream_t stream) {
  const float* F    = (const float*)d_in[0];   // [3136,512]
  const float* Wqkv = (const float*)d_in[1];   // [1536,512]
  const float* bqkv = (const float*)d_in[2];   // [1536]
  const float* Wo   = (const float*)d_in[3];   // [512,512]
  const float* bo   = (const float*)d_in[4];   // [512]
  const float* W1   = (const float*)d_in[5];   // [512,512]
  const float* b1   = (const float*)d_in[6];   // [512]
  const float* lng  = (const float*)d_in[7];   // [512]
  const float* lnb  = (const float*)d_in[8];   // [512]
  const float* W2   = (const float*)d_in[9];   // [20,512]
  const float* b2   = (const float*)d_in[10];  // [20]
  const float* Tm   = (const float*)d_in[11];  // [20,512]
  float* out = (float*)d_out;

  float* ws     = (float*)d_ws;
  float* qkv    = ws;                    // 3136*1536 = 4,816,896
  float* scores = qkv + 4816896;         // 128*196*196 = 4,917,248
  float* Omg    = scores + 4917248;      // 3136*512
  float* Fenh   = Omg + 1605632;         // 3136*512
  float* h1     = Fenh + 1605632;        // 3136*512
  float* Qp     = h1 + 1605632;          // 3136*20
  dim3 blk(256);

  // 1) qkv = F @ Wqkv^T + bqkv               [3136,1536]
  gemm_kernel<<<dim3(49, 24, 1), blk, 0, stream>>>(
      F, Wqkv, qkv, bqkv, nullptr,
      3136, 1536, 512, 512, 512, 1536,
      1, 0, 0, 0, 0, 0, 0, 1);

  // 2) scores[b,h] = Q[b,h] @ K[b,h]^T       [196,196] x 128 batches
  gemm_kernel<<<dim3(4, 4, 128), blk, 0, stream>>>(
      qkv, qkv + 512, scores, nullptr, nullptr,
      196, 196, 64, 1536, 1536, 196,
      8, 196LL * 1536, 64, 196LL * 1536, 64, 8LL * 38416, 38416, 1);

  // 3) softmax rows (scale 0.125 inside)
  softmax_kernel<<<dim3(6272), blk, 0, stream>>>(scores);

  // 4) O[b,h] = P[b,h] @ V[b,h]  -> merged [token, h*64+d]
  gemm_kernel<<<dim3(4, 1, 128), blk, 0, stream>>>(
      scores, qkv + 1024, Omg, nullptr, nullptr,
      196, 64, 196, 196, 1536, 512,
      8, 8LL * 38416, 38416, 196LL * 1536, 64, 196LL * 512, 64, 0);

  // 5) F_enh = O @ Wo^T + bo + F_clean
  gemm_kernel<<<dim3(49, 8, 1), blk, 0, stream>>>(
      Omg, Wo, Fenh, bo, F,
      3136, 512, 512, 512, 512, 512,
      1, 0, 0, 0, 0, 0, 0, 1);

  // 6) h1 = F_enh @ W1^T + b1
  gemm_kernel<<<dim3(49, 8, 1), blk, 0, stream>>>(
      Fenh, W1, h1, b1, nullptr,
      3136, 512, 512, 512, 512, 512,
      1, 0, 0, 0, 0, 0, 0, 1);

  // 7) LayerNorm + exact GELU (in place)
  lngelu_kernel<<<dim3(3136), blk, 0, stream>>>(h1, lng, lnb);

  // 8) Qp = h1 @ W2^T + b2
  w2_kernel<<<dim3(245), blk, 0, stream>>>(h1, W2, b2, Qp);

  // 9) outer product + abs-top-51 mask + L2 normalize + write [B,N,D,M]
  topk_kernel<<<dim3(3136), blk, 0, stream>>>(F, Tm, Qp, out);
}

// Round 4
// 433.164 us; speedup vs baseline: 1.3935x; 1.3935x over previous
//
#include <hip/hip_runtime.h>
#include <cmath>

// ---------------------------------------------------------------------------
// Problem constants: B=16, N=196, D=512, M=20, H=8, hd=64, k=51
//   tokens = 3136, 3D = 1536
// ---------------------------------------------------------------------------

// Generic small GEMM (64x64 tile), fp32 FMA + fp64 chunk accumulation.
// Used for the batched attention GEMMs (dims of 196/64 don't fit 128-tiles).
__global__ __launch_bounds__(256) void gemm_kernel(
    const float* __restrict__ A, const float* __restrict__ B,
    float* __restrict__ C, const float* __restrict__ bias,
    const float* __restrict__ res,
    int M, int N, int K, int lda, int ldb, int ldc,
    int zInner, long long aOuter, long long aInner,
    long long bOuter, long long bInner,
    long long cOuter, long long cInner, int bTrans)
{
  int z = blockIdx.z;
  int zo = z / zInner, zi = z % zInner;
  A += zo * aOuter + zi * aInner;
  B += zo * bOuter + zi * bInner;
  C += zo * cOuter + zi * cInner;

  __shared__ __align__(16) float As[16][68];
  __shared__ __align__(16) float Bs[16][68];

  int tid = threadIdx.x;
  int tx = tid & 15, ty = tid >> 4;
  int i0 = blockIdx.x * 64, j0 = blockIdx.y * 64;

  double acc[4][4];
#pragma unroll
  for (int i = 0; i < 4; i++)
#pragma unroll
    for (int j = 0; j < 4; j++) acc[i][j] = 0.0;

  for (int k0 = 0; k0 < K; k0 += 16) {
#pragma unroll
    for (int rr = 0; rr < 4; rr++) {
      int r = ty + 16 * rr;
      int gi = i0 + r, gk = k0 + tx;
      As[tx][r] = (gi < M && gk < K) ? A[(size_t)gi * lda + gk] : 0.0f;
    }
    if (bTrans) {
#pragma unroll
      for (int rr = 0; rr < 4; rr++) {
        int r = ty + 16 * rr;
        int gj = j0 + r, gk = k0 + tx;
        Bs[tx][r] = (gj < N && gk < K) ? B[(size_t)gj * ldb + gk] : 0.0f;
      }
    } else {
      int j = tid & 63, c0 = (tid >> 6) * 4;
#pragma unroll
      for (int cc = 0; cc < 4; cc++) {
        int c = c0 + cc;
        int gk = k0 + c, gj = j0 + j;
        Bs[c][j] = (gk < K && gj < N) ? B[(size_t)gk * ldb + gj] : 0.0f;
      }
    }
    __syncthreads();

    float cf[4][4];
#pragma unroll
    for (int i = 0; i < 4; i++)
#pragma unroll
      for (int j = 0; j < 4; j++) cf[i][j] = 0.0f;
#pragma unroll
    for (int kk = 0; kk < 16; kk++) {
      float4 a4 = *(const float4*)&As[kk][ty * 4];
      float4 b4 = *(const float4*)&Bs[kk][tx * 4];
      float av[4] = {a4.x, a4.y, a4.z, a4.w};
      float bv[4] = {b4.x, b4.y, b4.z, b4.w};
#pragma unroll
      for (int i = 0; i < 4; i++)
#pragma unroll
        for (int j = 0; j < 4; j++) cf[i][j] = fmaf(av[i], bv[j], cf[i][j]);
    }
#pragma unroll
    for (int i = 0; i < 4; i++)
#pragma unroll
      for (int j = 0; j < 4; j++) acc[i][j] += (double)cf[i][j];
    __syncthreads();
  }

#pragma unroll
  for (int i = 0; i < 4; i++) {
    int gi = i0 + ty * 4 + i;
    if (gi >= M) continue;
    int gj0 = j0 + tx * 4;
    if (gj0 >= N) continue;
    float ov[4];
#pragma unroll
    for (int j = 0; j < 4; j++) {
      double v = acc[i][j];
      if (bias) v += (double)bias[gj0 + j];
      if (res)  v += (double)res[(size_t)gi * ldc + gj0 + j];
      ov[j] = (float)v;
    }
    float4 o; o.x = ov[0]; o.y = ov[1]; o.z = ov[2]; o.w = ov[3];
    *(float4*)&C[(size_t)gi * ldc + gj0] = o;
  }
}

// 128x64 tile GEMM, 8x4 per thread, B transposed ([N][K] row-major), K%16==0,
// N%64==0. fp32 FMA + fp64 chunk accumulation (per 16-k chunk).
__global__ __launch_bounds__(256) void gemm128_kernel(
    const float* __restrict__ A, const float* __restrict__ B,
    float* __restrict__ C, const float* __restrict__ bias,
    const float* __restrict__ res,
    int M, int N, int K, int lda, int ldb, int ldc)
{
  __shared__ __align__(16) float As[16][136];  // [k][row], pad 136: conflict-free
  __shared__ __align__(16) float Bs[16][68];   // [k][col]

  int tid = threadIdx.x;
  int tx = tid & 15, ty = tid >> 4;            // tx: col quad, ty: row octet
  int i0 = blockIdx.x * 128, j0 = blockIdx.y * 64;

  // staging assignments
  int ar = tid >> 1, akb = (tid & 1) * 8;      // A: row, k-base (8 floats)
  int bj = tid >> 2, bkb = (tid & 3) * 4;      // B: col, k-base (4 floats)

  double acc[8][4];
#pragma unroll
  for (int i = 0; i < 8; i++)
#pragma unroll
    for (int j = 0; j < 4; j++) acc[i][j] = 0.0;

  for (int k0 = 0; k0 < K; k0 += 16) {
    int gi = i0 + ar;
    float4 a0 = {0, 0, 0, 0}, a1 = {0, 0, 0, 0};
    if (gi < M) {
      a0 = *(const float4*)&A[(size_t)gi * lda + k0 + akb];
      a1 = *(const float4*)&A[(size_t)gi * lda + k0 + akb + 4];
    }
    float4 b0 = *(const float4*)&B[(size_t)(j0 + bj) * ldb + k0 + bkb];
    __syncthreads();  // previous chunk's LDS reads complete
    {
      float av[8] = {a0.x, a0.y, a0.z, a0.w, a1.x, a1.y, a1.z, a1.w};
#pragma unroll
      for (int e = 0; e < 8; e++) As[akb + e][ar] = av[e];
      float bv[4] = {b0.x, b0.y, b0.z, b0.w};
#pragma unroll
      for (int e = 0; e < 4; e++) Bs[bkb + e][bj] = bv[e];
    }
    __syncthreads();

    float cf[8][4];
#pragma unroll
    for (int i = 0; i < 8; i++)
#pragma unroll
      for (int j = 0; j < 4; j++) cf[i][j] = 0.0f;
#pragma unroll
    for (int kk = 0; kk < 16; kk++) {
      float4 aA = *(const float4*)&As[kk][ty * 8];
      float4 aB = *(const float4*)&As[kk][ty * 8 + 4];
      float4 b4 = *(const float4*)&Bs[kk][tx * 4];
      float av[8] = {aA.x, aA.y, aA.z, aA.w, aB.x, aB.y, aB.z, aB.w};
      float bv[4] = {b4.x, b4.y, b4.z, b4.w};
#pragma unroll
      for (int i = 0; i < 8; i++)
#pragma unroll
        for (int j = 0; j < 4; j++) cf[i][j] = fmaf(av[i], bv[j], cf[i][j]);
    }
#pragma unroll
    for (int i = 0; i < 8; i++)
#pragma unroll
      for (int j = 0; j < 4; j++) acc[i][j] += (double)cf[i][j];
  }

#pragma unroll
  for (int i = 0; i < 8; i++) {
    int gi = i0 + ty * 8 + i;
    if (gi >= M) continue;
    int gj0 = j0 + tx * 4;
    float ov[4];
#pragma unroll
    for (int j = 0; j < 4; j++) {
      double v = acc[i][j];
      if (bias) v += (double)bias[gj0 + j];
      if (res)  v += (double)res[(size_t)gi * ldc + gj0 + j];
      ov[j] = (float)v;
    }
    float4 o; o.x = ov[0]; o.y = ov[1]; o.z = ov[2]; o.w = ov[3];
    *(float4*)&C[(size_t)gi * ldc + gj0] = o;
  }
}

// In-place row softmax of scaled scores: rows of length 196, scale 1/sqrt(64).
__global__ __launch_bounds__(256) void softmax_kernel(float* __restrict__ S)
{
  int row = blockIdx.x * 4 + (threadIdx.x >> 6);
  int lane = threadIdx.x & 63;
  float* sr = S + (size_t)row * 196;
  double v[4];
#pragma unroll
  for (int t = 0; t < 4; t++) {
    int j = lane + 64 * t;
    v[t] = (j < 196) ? (double)sr[j] * 0.125 : -1e300;
  }
  double mx = fmax(fmax(v[0], v[1]), fmax(v[2], v[3]));
#pragma unroll
  for (int off = 1; off < 64; off <<= 1) mx = fmax(mx, __shfl_xor(mx, off));
  double e[4]; double s = 0.0;
#pragma unroll
  for (int t = 0; t < 4; t++) {
    int j = lane + 64 * t;
    e[t] = (j < 196) ? exp(v[t] - mx) : 0.0;
    s += e[t];
  }
#pragma unroll
  for (int off = 1; off < 64; off <<= 1) s += __shfl_xor(s, off);
  double inv = 1.0 / s;
#pragma unroll
  for (int t = 0; t < 4; t++) {
    int j = lane + 64 * t;
    if (j < 196) sr[j] = (float)(e[t] * inv);
  }
}

// In-place LayerNorm (ddof=0, eps=1e-5) + exact GELU over rows of 512.
__global__ __launch_bounds__(256) void lngelu_kernel(float* __restrict__ H,
    const float* __restrict__ g, const float* __restrict__ bb)
{
  int row = blockIdx.x;
  float* hr = H + (size_t)row * 512;
  int tid = threadIdx.x, lane = tid & 63, wv = tid >> 6;
  __shared__ double red[8];
  double x0 = (double)hr[tid], x1 = (double)hr[tid + 256];
  double s = x0 + x1;
#pragma unroll
  for (int off = 1; off < 64; off <<= 1) s += __shfl_xor(s, off);
  if (lane == 0) red[wv] = s;
  __syncthreads();
  double mu = (red[0] + red[1] + red[2] + red[3]) * (1.0 / 512.0);
  double d0 = x0 - mu, d1 = x1 - mu;
  double q = d0 * d0 + d1 * d1;
#pragma unroll
  for (int off = 1; off < 64; off <<= 1) q += __shfl_xor(q, off);
  if (lane == 0) red[4 + wv] = q;
  __syncthreads();
  double var = (red[4] + red[5] + red[6] + red[7]) * (1.0 / 512.0);
  double inv = 1.0 / sqrt(var + 1e-5);
  double y0 = d0 * inv * (double)g[tid]       + (double)bb[tid];
  double y1 = d1 * inv * (double)g[tid + 256] + (double)bb[tid + 256];
  const double ISQRT2 = 0.70710678118654752440;
  double z0 = 0.5 * y0 * (1.0 + erf(y0 * ISQRT2));
  double z1 = 0.5 * y1 * (1.0 + erf(y1 * ISQRT2));
  hr[tid] = (float)z0;
  hr[tid + 256] = (float)z1;
}

// Qp[token,m] = h[token,:] . w2[m,:] + b2[m] ; fp64 accumulate.
__global__ __launch_bounds__(256) void w2_kernel(const float* __restrict__ H,
    const float* __restrict__ W2, const float* __restrict__ B2,
    float* __restrict__ Qp)
{
  int gidx = blockIdx.x * 256 + threadIdx.x;  // 245*256 == 62720 exactly
  int token = gidx / 20, m = gidx % 20;
  const float* hr = H + (size_t)token * 512;
  const float* wr = W2 + (size_t)m * 512;
  double acc = 0.0;
  for (int k = 0; k < 512; k += 4) {
    float4 hv = *(const float4*)&hr[k];
    float4 wv = *(const float4*)&wr[k];
    acc += (double)hv.x * wv.x + (double)hv.y * wv.y +
           (double)hv.z * wv.z + (double)hv.w * wv.w;
  }
  Qp[gidx] = (float)(acc + (double)B2[m]);
}

// Final: per (b,n,m) abs-top-51 over D of A=(F*T)*Qp, 0/1 mask, L2-normalize,
// write out[b,n,d,m]. Selection key = exact fp64 product bits (bit-exact vs a
// float64 reference, ties broken by lower d). Ballot-based counting: the
// candidate count is wave-uniform via __ballot + popcount (no shfl chains),
// and the selection mask IS the per-s ballot word -> 1.4 KB LDS total.
__global__ __launch_bounds__(256) void topk_kernel(
    const float* __restrict__ F, const float* __restrict__ T,
    const float* __restrict__ Qp, float* __restrict__ out)
{
  const int KSEL = 51;
  int bn = blockIdx.x;
  int tid = threadIdx.x, lane = tid & 63, wv = tid >> 6;
  __shared__ unsigned long long maskw[20][8];  // bit d of word s=d>>6 (bit=d&63)
  __shared__ float qif[20];                    // qp / max(|qp|*sqrt(ss), 1e-6)

  const float* Frow = F + (size_t)bn * 512;
  double f[8];
#pragma unroll
  for (int s = 0; s < 8; s++) f[s] = (double)Frow[lane + 64 * s];

  unsigned long long lmask = (1ULL << lane) - 1ULL;

#pragma unroll 1
  for (int t = 0; t < 5; t++) {
    int m = wv * 5 + t;
    double qp = (double)Qp[(size_t)bn * 20 + m];
    const float* Trow = T + (size_t)m * 512;
    unsigned long long u[8];
#pragma unroll
    for (int s = 0; s < 8; s++) {
      double p = f[s] * (double)Trow[lane + 64 * s];  // exact in fp64
      u[s] = ((unsigned long long)__double_as_longlong(p)) & 0x7fffffffffffffffULL;
    }
    // binary search smallest threshold with count(u >= thr) >= 51.
    // counts are wave-uniform (ballot+popc) -> uniform branches.
    unsigned long long lo = 0ULL, hi = 0x7ff0000000000000ULL;
    while (hi - lo > 1ULL) {
      unsigned long long mid = lo + ((hi - lo) >> 1);
      int c = 0;
#pragma unroll
      for (int s = 0; s < 8; s++) c += __popcll(__ballot(u[s] >= mid));
      if (c >= KSEL) { lo = mid; if (c == KSEL) break; }
      else hi = mid;
    }
    unsigned long long thr = lo;
    int cg = 0;
#pragma unroll
    for (int s = 0; s < 8; s++) cg += __popcll(__ballot(u[s] > thr));
    int need_eq = KSEL - cg;  // how many ==thr to take, in increasing d order
    int base = 0;
    unsigned long long selb[8];
    double ss = 0.0;
#pragma unroll
    for (int s = 0; s < 8; s++) {
      bool iseq = (u[s] == thr);
      unsigned long long bal = __ballot((int)iseq);
      int rk = base + __popcll(bal & lmask);
      bool sel = (u[s] > thr) || (iseq && rk < need_eq);
      base += __popcll(bal);
      selb[s] = __ballot((int)sel);
      if (sel) {
        double ap = __longlong_as_double((long long)u[s]);  // |p|
        ss += ap * ap;
      }
    }
#pragma unroll
    for (int off = 1; off < 64; off <<= 1) ss += __shfl_xor(ss, off);
    double nrm = fabs(qp) * sqrt(ss);
    double qid = qp / fmax(nrm, 1e-6);
    if (lane == 0) {
      qif[m] = (float)qid;
#pragma unroll
      for (int s = 0; s < 8; s++) maskw[m][s] = selb[s];
    }
  }
  __syncthreads();

  // writeout: lane owns d = tid, tid+256. T reads coalesced per m; mask/qif
  // reads are wave-broadcast; stores are float4 (L2 write-combines the
  // 80B-stride pattern; every output byte is written exactly once).
  float* orow = out + (size_t)bn * 10240;
#pragma unroll
  for (int half = 0; half < 2; half++) {
    int d = tid + half * 256;
    float fd = Frow[d];
    int dw = d >> 6;          // wave-uniform
    int db = d & 63;
    float vals[20];
#pragma unroll
    for (int m = 0; m < 20; m++) {
      unsigned long long w = maskw[m][dw];
      bool sel = (w >> db) & 1ULL;
      float tv = T[(size_t)m * 512 + d];
      vals[m] = sel ? fd * tv * qif[m] : 0.0f;
    }
#pragma unroll
    for (int q = 0; q < 5; q++) {
      float4 o;
      o.x = vals[q * 4 + 0];
      o.y = vals[q * 4 + 1];
      o.z = vals[q * 4 + 2];
      o.w = vals[q * 4 + 3];
      *(float4*)&orow[(size_t)d * 20 + q * 4] = o;
    }
  }
}

extern "C" void kernel_launch(void* const* d_in, const int* in_sizes, int n_in,
                              void* d_out, int out_size, void* d_ws, size_t ws_size,
                              hipStream_t stream) {
  const float* F    = (const float*)d_in[0];   // [3136,512]
  const float* Wqkv = (const float*)d_in[1];   // [1536,512]
  const float* bqkv = (const float*)d_in[2];   // [1536]
  const float* Wo   = (const float*)d_in[3];   // [512,512]
  const float* bo   = (const float*)d_in[4];   // [512]
  const float* W1   = (const float*)d_in[5];   // [512,512]
  const float* b1   = (const float*)d_in[6];   // [512]
  const float* lng  = (const float*)d_in[7];   // [512]
  const float* lnb  = (const float*)d_in[8];   // [512]
  const float* W2   = (const float*)d_in[9];   // [20,512]
  const float* b2   = (const float*)d_in[10];  // [20]
  const float* Tm   = (const float*)d_in[11];  // [20,512]
  float* out = (float*)d_out;

  float* ws     = (float*)d_ws;
  float* qkv    = ws;                    // 3136*1536
  float* scores = qkv + 4816896;         // 128*196*196
  float* Omg    = scores + 4917248;      // 3136*512
  float* Fenh   = Omg + 1605632;         // 3136*512
  float* h1     = Fenh + 1605632;        // 3136*512
  float* Qp     = h1 + 1605632;          // 3136*20
  dim3 blk(256);

  // 1) qkv = F @ Wqkv^T + bqkv               [3136,1536]
  gemm128_kernel<<<dim3(25, 24), blk, 0, stream>>>(
      F, Wqkv, qkv, bqkv, nullptr, 3136, 1536, 512, 512, 512, 1536);

  // 2) scores[b,h] = Q[b,h] @ K[b,h]^T       [196,196] x 128 batches
  gemm_kernel<<<dim3(4, 4, 128), blk, 0, stream>>>(
      qkv, qkv + 512, scores, nullptr, nullptr,
      196, 196, 64, 1536, 1536, 196,
      8, 196LL * 1536, 64, 196LL * 1536, 64, 8LL * 38416, 38416, 1);

  // 3) softmax rows (scale 0.125 inside)
  softmax_kernel<<<dim3(6272), blk, 0, stream>>>(scores);

  // 4) O[b,h] = P[b,h] @ V[b,h]  -> merged [token, h*64+d]
  gemm_kernel<<<dim3(4, 1, 128), blk, 0, stream>>>(
      scores, qkv + 1024, Omg, nullptr, nullptr,
      196, 64, 196, 196, 1536, 512,
      8, 8LL * 38416, 38416, 196LL * 1536, 64, 196LL * 512, 64, 0);

  // 5) F_enh = O @ Wo^T + bo + F_clean
  gemm128_kernel<<<dim3(25, 8), blk, 0, stream>>>(
      Omg, Wo, Fenh, bo, F, 3136, 512, 512, 512, 512, 512);

  // 6) h1 = F_enh @ W1^T + b1
  gemm128_kernel<<<dim3(25, 8), blk, 0, stream>>>(
      Fenh, W1, h1, b1, nullptr, 3136, 512, 512, 512, 512, 512);

  // 7) LayerNorm + exact GELU (in place)
  lngelu_kernel<<<dim3(3136), blk, 0, stream>>>(h1, lng, lnb);

  // 8) Qp = h1 @ W2^T + b2
  w2_kernel<<<dim3(245), blk, 0, stream>>>(h1, W2, b2, Qp);

  // 9) outer product + abs-top-51 mask + L2 normalize + write [B,N,D,M]
  topk_kernel<<<dim3(3136), blk, 0, stream>>>(F, Tm, Qp, out);
}

// Round 5
// 397.786 us; speedup vs baseline: 1.5174x; 1.0889x over previous
//
#include <hip/hip_runtime.h>
#include <cmath>

// ---------------------------------------------------------------------------
// Problem constants: B=16, N=196, D=512, M=20, H=8, hd=64, k=51
//   tokens = 3136, 3D = 1536
// ---------------------------------------------------------------------------

typedef __attribute__((ext_vector_type(8))) short bf16x8v;
typedef __attribute__((ext_vector_type(4))) float f32x4v;

__device__ __forceinline__ unsigned short f2bf_rne(float x) {
  unsigned u = __float_as_uint(x);
  u += 0x7fffu + ((u >> 16) & 1u);   // round-to-nearest-even
  return (unsigned short)(u >> 16);
}
__device__ __forceinline__ float bf2f(unsigned short h) {
  return __uint_as_float(((unsigned)h) << 16);
}

// ---------------------------------------------------------------------------
// bf16x3 emulated-fp32 MFMA GEMM: C[i,j] = sum_k A[i,k]*B[j,k] (+bias[j])
// (+res[i,j]).  A:[M][K] lda, B:[N][K] ldb (i.e. B^T form), C:[M][N] ldc.
// Requires K%32==0, N%128==0; M guarded. Each fp32 is split on-the-fly into
// 3 bf16 limbs (exact Sterbenz residuals, |eps|<=2^-27|x|); 6 MFMA products
// (limb pairs i+j<=2) accumulate small-first into the fp32 MFMA accumulator.
// Block: 256 thr = 4 waves (2x2); wave tile 64x64 = 4x4 frags of 16x16.
// ---------------------------------------------------------------------------
#define GBM 128
#define GBK 32
#define AROWB 80                 // LDS bytes per row (40 bf16): 2-way banks
#define SPLIT_SZ (128 * AROWB)   // 10240 B per limb plane
#define BBASE (3 * SPLIT_SZ)     // B tile base: 30720

__global__ __launch_bounds__(256) void gemm_bf16x3_kernel(
    const float* __restrict__ A, const float* __restrict__ B,
    float* __restrict__ C, const float* __restrict__ bias,
    const float* __restrict__ res,
    int M, int N, int K, int lda, int ldb, int ldc)
{
  __shared__ __align__(16) unsigned char smem[2 * BBASE];  // 61440 B

  int tid = threadIdx.x;
  int lane = tid & 63, w = tid >> 6;
  int wrow = w >> 1, wcol = w & 1;
  int i0 = blockIdx.x * GBM, j0 = blockIdx.y * 128;

  // staging: thread covers one row-half (16 fp32) of A tile and of B tile
  int srow = tid >> 1;                 // 0..127
  int skh  = tid & 1;                  // which 16-k half
  int arow = i0 + srow; if (arow > M - 1) arow = M - 1;
  const float* aptr = A + (size_t)arow * lda + skh * 16;
  const float* bptr = B + (size_t)(j0 + srow) * ldb + skh * 16;
  unsigned swoff = (unsigned)srow * AROWB + (unsigned)skh * 32;

  f32x4v acc[4][4];
#pragma unroll
  for (int fi = 0; fi < 4; fi++)
#pragma unroll
    for (int fj = 0; fj < 4; fj++) acc[fi][fj] = (f32x4v){0.f, 0.f, 0.f, 0.f};

  // frag read base offsets (row*AROWB + kgroup*16)
  unsigned fr_a = (unsigned)(wrow * 64 + (lane & 15)) * AROWB + (unsigned)(lane >> 4) * 16;
  unsigned fr_b = (unsigned)(wcol * 64 + (lane & 15)) * AROWB + (unsigned)(lane >> 4) * 16 + BBASE;

  for (int k0 = 0; k0 < K; k0 += GBK) {
    // ---- load 16 fp32 of A-row-half and B-row-half ----
    float av[16], bv[16];
    {
      const float4 q0 = *(const float4*)(aptr + k0);
      const float4 q1 = *(const float4*)(aptr + k0 + 4);
      const float4 q2 = *(const float4*)(aptr + k0 + 8);
      const float4 q3 = *(const float4*)(aptr + k0 + 12);
      av[0]=q0.x; av[1]=q0.y; av[2]=q0.z; av[3]=q0.w;
      av[4]=q1.x; av[5]=q1.y; av[6]=q1.z; av[7]=q1.w;
      av[8]=q2.x; av[9]=q2.y; av[10]=q2.z; av[11]=q2.w;
      av[12]=q3.x; av[13]=q3.y; av[14]=q3.z; av[15]=q3.w;
      const float4 r0 = *(const float4*)(bptr + k0);
      const float4 r1 = *(const float4*)(bptr + k0 + 4);
      const float4 r2 = *(const float4*)(bptr + k0 + 8);
      const float4 r3 = *(const float4*)(bptr + k0 + 12);
      bv[0]=r0.x; bv[1]=r0.y; bv[2]=r0.z; bv[3]=r0.w;
      bv[4]=r1.x; bv[5]=r1.y; bv[6]=r1.z; bv[7]=r1.w;
      bv[8]=r2.x; bv[9]=r2.y; bv[10]=r2.z; bv[11]=r2.w;
      bv[12]=r3.x; bv[13]=r3.y; bv[14]=r3.z; bv[15]=r3.w;
    }
    // ---- split into 3 bf16 limbs each ----
    unsigned short ha[3][16], hb[3][16];
#pragma unroll
    for (int e = 0; e < 16; e++) {
      float x = av[e];
      unsigned short s0 = f2bf_rne(x); float r = x - bf2f(s0);
      unsigned short s1 = f2bf_rne(r); float r2 = r - bf2f(s1);
      unsigned short s2 = f2bf_rne(r2);
      ha[0][e] = s0; ha[1][e] = s1; ha[2][e] = s2;
      float y = bv[e];
      unsigned short t0 = f2bf_rne(y); float u = y - bf2f(t0);
      unsigned short t1 = f2bf_rne(u); float u2 = u - bf2f(t1);
      unsigned short t2 = f2bf_rne(u2);
      hb[0][e] = t0; hb[1][e] = t1; hb[2][e] = t2;
    }
    __syncthreads();  // previous chunk's frag reads complete
#pragma unroll
    for (int s = 0; s < 3; s++) {
      bf16x8v v0, v1, w0, w1;
#pragma unroll
      for (int e = 0; e < 8; e++) {
        v0[e] = (short)ha[s][e]; v1[e] = (short)ha[s][8 + e];
        w0[e] = (short)hb[s][e]; w1[e] = (short)hb[s][8 + e];
      }
      *(bf16x8v*)(smem + s * SPLIT_SZ + swoff)              = v0;
      *(bf16x8v*)(smem + s * SPLIT_SZ + swoff + 16)         = v1;
      *(bf16x8v*)(smem + BBASE + s * SPLIT_SZ + swoff)      = w0;
      *(bf16x8v*)(smem + BBASE + s * SPLIT_SZ + swoff + 16) = w1;
    }
    __syncthreads();

    // ---- fragment reads + MFMA ----
    bf16x8v af[4][3];
#pragma unroll
    for (int fi = 0; fi < 4; fi++)
#pragma unroll
      for (int s = 0; s < 3; s++)
        af[fi][s] = *(const bf16x8v*)(smem + s * SPLIT_SZ + fr_a + fi * (16 * AROWB));

#pragma unroll
    for (int fj = 0; fj < 4; fj++) {
      bf16x8v b0 = *(const bf16x8v*)(smem + 0 * SPLIT_SZ + fr_b + fj * (16 * AROWB));
      bf16x8v b1 = *(const bf16x8v*)(smem + 1 * SPLIT_SZ + fr_b + fj * (16 * AROWB));
      bf16x8v b2 = *(const bf16x8v*)(smem + 2 * SPLIT_SZ + fr_b + fj * (16 * AROWB));
#pragma unroll
      for (int fi = 0; fi < 4; fi++) {
        f32x4v c = acc[fi][fj];
        // small-scale products first (2^-18), then 2^-9, then main
        c = __builtin_amdgcn_mfma_f32_16x16x32_bf16(af[fi][2], b0, c, 0, 0, 0);
        c = __builtin_amdgcn_mfma_f32_16x16x32_bf16(af[fi][1], b1, c, 0, 0, 0);
        c = __builtin_amdgcn_mfma_f32_16x16x32_bf16(af[fi][0], b2, c, 0, 0, 0);
        c = __builtin_amdgcn_mfma_f32_16x16x32_bf16(af[fi][1], b0, c, 0, 0, 0);
        c = __builtin_amdgcn_mfma_f32_16x16x32_bf16(af[fi][0], b1, c, 0, 0, 0);
        c = __builtin_amdgcn_mfma_f32_16x16x32_bf16(af[fi][0], b0, c, 0, 0, 0);
        acc[fi][fj] = c;
      }
    }
  }

  // ---- epilogue: C/D layout col=lane&15, row=(lane>>4)*4+reg (m89) ----
#pragma unroll
  for (int fi = 0; fi < 4; fi++) {
    int row0 = i0 + wrow * 64 + fi * 16 + (lane >> 4) * 4;
#pragma unroll
    for (int fj = 0; fj < 4; fj++) {
      int col = j0 + wcol * 64 + fj * 16 + (lane & 15);
      float badd = bias ? bias[col] : 0.0f;
      f32x4v v = acc[fi][fj];
#pragma unroll
      for (int r = 0; r < 4; r++) {
        int row = row0 + r;
        if (row < M) {
          float o = v[r] + badd;
          if (res) o += res[(size_t)row * ldc + col];
          C[(size_t)row * ldc + col] = o;
        }
      }
    }
  }
}

// ---------------------------------------------------------------------------
// Generic small GEMM (64x64 tile), fp32 FMA + fp64 chunk accumulation.
// Used for the batched attention GEMMs (dims of 196/64).
// ---------------------------------------------------------------------------
__global__ __launch_bounds__(256) void gemm_kernel(
    const float* __restrict__ A, const float* __restrict__ B,
    float* __restrict__ C, const float* __restrict__ bias,
    const float* __restrict__ res,
    int M, int N, int K, int lda, int ldb, int ldc,
    int zInner, long long aOuter, long long aInner,
    long long bOuter, long long bInner,
    long long cOuter, long long cInner, int bTrans)
{
  int z = blockIdx.z;
  int zo = z / zInner, zi = z % zInner;
  A += zo * aOuter + zi * aInner;
  B += zo * bOuter + zi * bInner;
  C += zo * cOuter + zi * cInner;

  __shared__ __align__(16) float As[16][68];
  __shared__ __align__(16) float Bs[16][68];

  int tid = threadIdx.x;
  int tx = tid & 15, ty = tid >> 4;
  int i0 = blockIdx.x * 64, j0 = blockIdx.y * 64;

  double acc[4][4];
#pragma unroll
  for (int i = 0; i < 4; i++)
#pragma unroll
    for (int j = 0; j < 4; j++) acc[i][j] = 0.0;

  for (int k0 = 0; k0 < K; k0 += 16) {
#pragma unroll
    for (int rr = 0; rr < 4; rr++) {
      int r = ty + 16 * rr;
      int gi = i0 + r, gk = k0 + tx;
      As[tx][r] = (gi < M && gk < K) ? A[(size_t)gi * lda + gk] : 0.0f;
    }
    if (bTrans) {
#pragma unroll
      for (int rr = 0; rr < 4; rr++) {
        int r = ty + 16 * rr;
        int gj = j0 + r, gk = k0 + tx;
        Bs[tx][r] = (gj < N && gk < K) ? B[(size_t)gj * ldb + gk] : 0.0f;
      }
    } else {
      int j = tid & 63, c0 = (tid >> 6) * 4;
#pragma unroll
      for (int cc = 0; cc < 4; cc++) {
        int c = c0 + cc;
        int gk = k0 + c, gj = j0 + j;
        Bs[c][j] = (gk < K && gj < N) ? B[(size_t)gk * ldb + gj] : 0.0f;
      }
    }
    __syncthreads();

    float cf[4][4];
#pragma unroll
    for (int i = 0; i < 4; i++)
#pragma unroll
      for (int j = 0; j < 4; j++) cf[i][j] = 0.0f;
#pragma unroll
    for (int kk = 0; kk < 16; kk++) {
      float4 a4 = *(const float4*)&As[kk][ty * 4];
      float4 b4 = *(const float4*)&Bs[kk][tx * 4];
      float av[4] = {a4.x, a4.y, a4.z, a4.w};
      float bv[4] = {b4.x, b4.y, b4.z, b4.w};
#pragma unroll
      for (int i = 0; i < 4; i++)
#pragma unroll
        for (int j = 0; j < 4; j++) cf[i][j] = fmaf(av[i], bv[j], cf[i][j]);
    }
#pragma unroll
    for (int i = 0; i < 4; i++)
#pragma unroll
      for (int j = 0; j < 4; j++) acc[i][j] += (double)cf[i][j];
    __syncthreads();
  }

#pragma unroll
  for (int i = 0; i < 4; i++) {
    int gi = i0 + ty * 4 + i;
    if (gi >= M) continue;
    int gj0 = j0 + tx * 4;
    if (gj0 >= N) continue;
    float ov[4];
#pragma unroll
    for (int j = 0; j < 4; j++) {
      double v = acc[i][j];
      if (bias) v += (double)bias[gj0 + j];
      if (res)  v += (double)res[(size_t)gi * ldc + gj0 + j];
      ov[j] = (float)v;
    }
    float4 o; o.x = ov[0]; o.y = ov[1]; o.z = ov[2]; o.w = ov[3];
    *(float4*)&C[(size_t)gi * ldc + gj0] = o;
  }
}

// In-place row softmax of scaled scores: rows of length 196, scale 1/sqrt(64).
__global__ __launch_bounds__(256) void softmax_kernel(float* __restrict__ S)
{
  int row = blockIdx.x * 4 + (threadIdx.x >> 6);
  int lane = threadIdx.x & 63;
  float* sr = S + (size_t)row * 196;
  double v[4];
#pragma unroll
  for (int t = 0; t < 4; t++) {
    int j = lane + 64 * t;
    v[t] = (j < 196) ? (double)sr[j] * 0.125 : -1e300;
  }
  double mx = fmax(fmax(v[0], v[1]), fmax(v[2], v[3]));
#pragma unroll
  for (int off = 1; off < 64; off <<= 1) mx = fmax(mx, __shfl_xor(mx, off));
  double e[4]; double s = 0.0;
#pragma unroll
  for (int t = 0; t < 4; t++) {
    int j = lane + 64 * t;
    e[t] = (j < 196) ? exp(v[t] - mx) : 0.0;
    s += e[t];
  }
#pragma unroll
  for (int off = 1; off < 64; off <<= 1) s += __shfl_xor(s, off);
  double inv = 1.0 / s;
#pragma unroll
  for (int t = 0; t < 4; t++) {
    int j = lane + 64 * t;
    if (j < 196) sr[j] = (float)(e[t] * inv);
  }
}

// In-place LayerNorm (ddof=0, eps=1e-5) + exact GELU over rows of 512.
__global__ __launch_bounds__(256) void lngelu_kernel(float* __restrict__ H,
    const float* __restrict__ g, const float* __restrict__ bb)
{
  int row = blockIdx.x;
  float* hr = H + (size_t)row * 512;
  int tid = threadIdx.x, lane = tid & 63, wv = tid >> 6;
  __shared__ double red[8];
  double x0 = (double)hr[tid], x1 = (double)hr[tid + 256];
  double s = x0 + x1;
#pragma unroll
  for (int off = 1; off < 64; off <<= 1) s += __shfl_xor(s, off);
  if (lane == 0) red[wv] = s;
  __syncthreads();
  double mu = (red[0] + red[1] + red[2] + red[3]) * (1.0 / 512.0);
  double d0 = x0 - mu, d1 = x1 - mu;
  double q = d0 * d0 + d1 * d1;
#pragma unroll
  for (int off = 1; off < 64; off <<= 1) q += __shfl_xor(q, off);
  if (lane == 0) red[4 + wv] = q;
  __syncthreads();
  double var = (red[4] + red[5] + red[6] + red[7]) * (1.0 / 512.0);
  double inv = 1.0 / sqrt(var + 1e-5);
  double y0 = d0 * inv * (double)g[tid]       + (double)bb[tid];
  double y1 = d1 * inv * (double)g[tid + 256] + (double)bb[tid + 256];
  const double ISQRT2 = 0.70710678118654752440;
  double z0 = 0.5 * y0 * (1.0 + erf(y0 * ISQRT2));
  double z1 = 0.5 * y1 * (1.0 + erf(y1 * ISQRT2));
  hr[tid] = (float)z0;
  hr[tid + 256] = (float)z1;
}

// Qp[token,m] = h[token,:] . w2[m,:] + b2[m] ; fp64 accumulate.
__global__ __launch_bounds__(256) void w2_kernel(const float* __restrict__ H,
    const float* __restrict__ W2, const float* __restrict__ B2,
    float* __restrict__ Qp)
{
  int gidx = blockIdx.x * 256 + threadIdx.x;  // 245*256 == 62720 exactly
  int token = gidx / 20, m = gidx % 20;
  const float* hr = H + (size_t)token * 512;
  const float* wr = W2 + (size_t)m * 512;
  double acc = 0.0;
  for (int k = 0; k < 512; k += 4) {
    float4 hv = *(const float4*)&hr[k];
    float4 wv = *(const float4*)&wr[k];
    acc += (double)hv.x * wv.x + (double)hv.y * wv.y +
           (double)hv.z * wv.z + (double)hv.w * wv.w;
  }
  Qp[gidx] = (float)(acc + (double)B2[m]);
}

// Final: per (b,n,m) abs-top-51 over D of A=(F*T)*Qp, 0/1 mask, L2-normalize,
// write out[b,n,d,m]. Selection key = exact fp64 product bits; ballot-based
// counting (wave-uniform); mask stored as 8 ballot words per m.
__global__ __launch_bounds__(256) void topk_kernel(
    const float* __restrict__ F, const float* __restrict__ T,
    const float* __restrict__ Qp, float* __restrict__ out)
{
  const int KSEL = 51;
  int bn = blockIdx.x;
  int tid = threadIdx.x, lane = tid & 63, wv = tid >> 6;
  __shared__ unsigned long long maskw[20][8];
  __shared__ float qif[20];

  const float* Frow = F + (size_t)bn * 512;
  double f[8];
#pragma unroll
  for (int s = 0; s < 8; s++) f[s] = (double)Frow[lane + 64 * s];

  unsigned long long lmask = (1ULL << lane) - 1ULL;

#pragma unroll 1
  for (int t = 0; t < 5; t++) {
    int m = wv * 5 + t;
    double qp = (double)Qp[(size_t)bn * 20 + m];
    const float* Trow = T + (size_t)m * 512;
    unsigned long long u[8];
#pragma unroll
    for (int s = 0; s < 8; s++) {
      double p = f[s] * (double)Trow[lane + 64 * s];  // exact in fp64
      u[s] = ((unsigned long long)__double_as_longlong(p)) & 0x7fffffffffffffffULL;
    }
    unsigned long long lo = 0ULL, hi = 0x7ff0000000000000ULL;
    while (hi - lo > 1ULL) {
      unsigned long long mid = lo + ((hi - lo) >> 1);
      int c = 0;
#pragma unroll
      for (int s = 0; s < 8; s++) c += __popcll(__ballot(u[s] >= mid));
      if (c >= KSEL) { lo = mid; if (c == KSEL) break; }
      else hi = mid;
    }
    unsigned long long thr = lo;
    int cg = 0;
#pragma unroll
    for (int s = 0; s < 8; s++) cg += __popcll(__ballot(u[s] > thr));
    int need_eq = KSEL - cg;
    int base = 0;
    unsigned long long selb[8];
    double ss = 0.0;
#pragma unroll
    for (int s = 0; s < 8; s++) {
      bool iseq = (u[s] == thr);
      unsigned long long bal = __ballot((int)iseq);
      int rk = base + __popcll(bal & lmask);
      bool sel = (u[s] > thr) || (iseq && rk < need_eq);
      base += __popcll(bal);
      selb[s] = __ballot((int)sel);
      if (sel) {
        double ap = __longlong_as_double((long long)u[s]);
        ss += ap * ap;
      }
    }
#pragma unroll
    for (int off = 1; off < 64; off <<= 1) ss += __shfl_xor(ss, off);
    double nrm = fabs(qp) * sqrt(ss);
    double qid = qp / fmax(nrm, 1e-6);
    if (lane == 0) {
      qif[m] = (float)qid;
#pragma unroll
      for (int s = 0; s < 8; s++) maskw[m][s] = selb[s];
    }
  }
  __syncthreads();

  float* orow = out + (size_t)bn * 10240;
#pragma unroll
  for (int half = 0; half < 2; half++) {
    int d = tid + half * 256;
    float fd = Frow[d];
    int dw = d >> 6;
    int db = d & 63;
    float vals[20];
#pragma unroll
    for (int m = 0; m < 20; m++) {
      unsigned long long ww = maskw[m][dw];
      bool sel = (ww >> db) & 1ULL;
      float tv = T[(size_t)m * 512 + d];
      vals[m] = sel ? fd * tv * qif[m] : 0.0f;
    }
#pragma unroll
    for (int q = 0; q < 5; q++) {
      float4 o;
      o.x = vals[q * 4 + 0];
      o.y = vals[q * 4 + 1];
      o.z = vals[q * 4 + 2];
      o.w = vals[q * 4 + 3];
      *(float4*)&orow[(size_t)d * 20 + q * 4] = o;
    }
  }
}

extern "C" void kernel_launch(void* const* d_in, const int* in_sizes, int n_in,
                              void* d_out, int out_size, void* d_ws, size_t ws_size,
                              hipStream_t stream) {
  const float* F    = (const float*)d_in[0];   // [3136,512]
  const float* Wqkv = (const float*)d_in[1];   // [1536,512]
  const float* bqkv = (const float*)d_in[2];   // [1536]
  const float* Wo   = (const float*)d_in[3];   // [512,512]
  const float* bo   = (const float*)d_in[4];   // [512]
  const float* W1   = (const float*)d_in[5];   // [512,512]
  const float* b1   = (const float*)d_in[6];   // [512]
  const float* lng  = (const float*)d_in[7];   // [512]
  const float* lnb  = (const float*)d_in[8];   // [512]
  const float* W2   = (const float*)d_in[9];   // [20,512]
  const float* b2   = (const float*)d_in[10];  // [20]
  const float* Tm   = (const float*)d_in[11];  // [20,512]
  float* out = (float*)d_out;

  float* ws     = (float*)d_ws;
  float* qkv    = ws;                    // 3136*1536
  float* scores = qkv + 4816896;         // 128*196*196
  float* Omg    = scores + 4917248;      // 3136*512
  float* Fenh   = Omg + 1605632;         // 3136*512
  float* h1     = Fenh + 1605632;        // 3136*512
  float* Qp     = h1 + 1605632;          // 3136*20
  dim3 blk(256);

  // 1) qkv = F @ Wqkv^T + bqkv               [3136,1536]  (bf16x3 MFMA)
  gemm_bf16x3_kernel<<<dim3(25, 12), blk, 0, stream>>>(
      F, Wqkv, qkv, bqkv, nullptr, 3136, 1536, 512, 512, 512, 1536);

  // 2) scores[b,h] = Q[b,h] @ K[b,h]^T       [196,196] x 128 batches
  gemm_kernel<<<dim3(4, 4, 128), blk, 0, stream>>>(
      qkv, qkv + 512, scores, nullptr, nullptr,
      196, 196, 64, 1536, 1536, 196,
      8, 196LL * 1536, 64, 196LL * 1536, 64, 8LL * 38416, 38416, 1);

  // 3) softmax rows (scale 0.125 inside)
  softmax_kernel<<<dim3(6272), blk, 0, stream>>>(scores);

  // 4) O[b,h] = P[b,h] @ V[b,h]  -> merged [token, h*64+d]
  gemm_kernel<<<dim3(4, 1, 128), blk, 0, stream>>>(
      scores, qkv + 1024, Omg, nullptr, nullptr,
      196, 64, 196, 196, 1536, 512,
      8, 8LL * 38416, 38416, 196LL * 1536, 64, 196LL * 512, 64, 0);

  // 5) F_enh = O @ Wo^T + bo + F_clean       (bf16x3 MFMA)
  gemm_bf16x3_kernel<<<dim3(25, 4), blk, 0, stream>>>(
      Omg, Wo, Fenh, bo, F, 3136, 512, 512, 512, 512, 512);

  // 6) h1 = F_enh @ W1^T + b1                (bf16x3 MFMA)
  gemm_bf16x3_kernel<<<dim3(25, 4), blk, 0, stream>>>(
      Fenh, W1, h1, b1, nullptr, 3136, 512, 512, 512, 512, 512);

  // 7) LayerNorm + exact GELU (in place)
  lngelu_kernel<<<dim3(3136), blk, 0, stream>>>(h1, lng, lnb);

  // 8) Qp = h1 @ W2^T + b2
  w2_kernel<<<dim3(245), blk, 0, stream>>>(h1, W2, b2, Qp);

  // 9) outer product + abs-top-51 mask + L2 normalize + write [B,N,D,M]
  topk_kernel<<<dim3(3136), blk, 0, stream>>>(F, Tm, Qp, out);
}